// Round 1
// baseline (482.901 us; speedup 1.0000x reference)
//
#include <hip/hip_runtime.h>

// Problem constants
static constexpr int Bn  = 64;     // batch
static constexpr int T   = 2048;   // angles
static constexpr int NA  = 256;    // atoms
static constexpr int DA  = 256;    // d_atom (K1)
static constexpr int DH  = 512;    // d_hid  (N1 / K2)
static constexpr int DO  = 256;    // d_out  (N2)
static constexpr int M   = Bn * T;         // 131072 rows
static constexpr int MT1 = M / 64;         // 2048 m-tiles of 64 rows

typedef __attribute__((ext_vector_type(4))) float  f32x4;
typedef __attribute__((ext_vector_type(8))) __bf16 bf16x8;
typedef __attribute__((ext_vector_type(8))) short  short8;

__device__ __forceinline__ unsigned short f2bf(float f) {
  union { float f; unsigned u; } v; v.f = f;
  unsigned u = v.u + 0x7FFFu + ((v.u >> 16) & 1u);   // RNE
  return (unsigned short)(u >> 16);
}
__device__ __forceinline__ float bf2f(unsigned short b) {
  union { unsigned u; float f; } v; v.u = ((unsigned)b) << 16;
  return v.f;
}

// ---------------------------------------------------------------------------
// prep: W1 [256x512] f32 -> W1T [512][256] bf16 ; W2 [512x256] f32 -> W2T [256][512] bf16
// ---------------------------------------------------------------------------
__global__ void prep_kernel(const float* __restrict__ W1, const float* __restrict__ W2,
                            unsigned short* __restrict__ W1T, unsigned short* __restrict__ W2T) {
  int id = blockIdx.x * 256 + threadIdx.x;           // 131072 threads
  {
    int n = id >> 8, k = id & 255;                   // W1T[n][k] = W1[k][n]
    W1T[id] = f2bf(W1[k * DH + n]);
  }
  {
    int n = id >> 9, k = id & 511;                   // W2T[n][k] = W2[k][n]
    W2T[id] = f2bf(W2[k * DO + n]);
  }
}

// ---------------------------------------------------------------------------
// k1: gather(z,idx) -> x[64 x 256] -> h = x@W1 + b1 (bf16 store) + column partial stats
// grid: 2048 blocks (one per 64-row tile), 256 threads (4 waves)
// wave w computes rows 0..63 x cols [w*128, w*128+128)
// ---------------------------------------------------------------------------
__global__ __launch_bounds__(256) void k1_gemm1(
    const float* __restrict__ z, const int* __restrict__ tbl,
    const unsigned short* __restrict__ W1T, const float* __restrict__ b1,
    unsigned short* __restrict__ hbuf, float* __restrict__ psum, float* __restrict__ psumsq) {
  __shared__ __align__(16) unsigned short As[64][40];    // 32 valid + 8 pad
  __shared__ __align__(16) unsigned short Bs[DH][40];    // [n][k] transposed W1 slice
  __shared__ int idxs[64][3];

  const int tid   = threadIdx.x;
  const int mtile = blockIdx.x;
  const int row0  = mtile * 64;
  const int b     = row0 >> 11;                      // T = 2048
  const float* zb = z + (size_t)b * NA * DA;

  if (tid < 192) ((int*)idxs)[tid] = tbl[row0 * 3 + tid];
  __syncthreads();

  const int wave = tid >> 6, lane = tid & 63;
  const int q = lane >> 4, r16 = lane & 15;
  const int gr = tid >> 2, sub = tid & 3;            // gather: 4 threads/row, 8 floats each

  f32x4 acc[4][8] = {};

  for (int k0 = 0; k0 < DA; k0 += 32) {
    // ---- stage A: gather-sum 3 z-rows, convert to bf16 ----
    {
      const float* p0 = zb + idxs[gr][0] * DA + k0 + sub * 8;
      const float* p1 = zb + idxs[gr][1] * DA + k0 + sub * 8;
      const float* p2 = zb + idxs[gr][2] * DA + k0 + sub * 8;
      float4 a0 = *(const float4*)p0, a1 = *(const float4*)(p0 + 4);
      float4 b0 = *(const float4*)p1, b1v = *(const float4*)(p1 + 4);
      float4 c0 = *(const float4*)p2, c1 = *(const float4*)(p2 + 4);
      float s[8];
      s[0] = a0.x + b0.x + c0.x;  s[1] = a0.y + b0.y + c0.y;
      s[2] = a0.z + b0.z + c0.z;  s[3] = a0.w + b0.w + c0.w;
      s[4] = a1.x + b1v.x + c1.x; s[5] = a1.y + b1v.y + c1.y;
      s[6] = a1.z + b1v.z + c1.z; s[7] = a1.w + b1v.w + c1.w;
      short8 pk;
#pragma unroll
      for (int j = 0; j < 8; j++) pk[j] = (short)f2bf(s[j]);
      *(short8*)&As[gr][sub * 8] = pk;
    }
    // ---- stage B: copy W1T[n][k0..k0+31] for all 512 n ----
    {
#pragma unroll
      for (int sdx = 0; sdx < 2; sdx++) {
        int n = tid + sdx * 256;
        const unsigned short* src = W1T + n * DA + k0;
#pragma unroll
        for (int i = 0; i < 4; i++)
          *(short8*)&Bs[n][i * 8] = *(const short8*)(src + i * 8);
      }
    }
    __syncthreads();

    const int n0 = wave * 128;
    bf16x8 afr[4], bfr[8];
#pragma unroll
    for (int mf = 0; mf < 4; mf++) afr[mf] = *(const bf16x8*)&As[mf * 16 + r16][q * 8];
#pragma unroll
    for (int nf = 0; nf < 8; nf++) bfr[nf] = *(const bf16x8*)&Bs[n0 + nf * 16 + r16][q * 8];
#pragma unroll
    for (int mf = 0; mf < 4; mf++)
#pragma unroll
      for (int nf = 0; nf < 8; nf++)
        acc[mf][nf] = __builtin_amdgcn_mfma_f32_16x16x32_bf16(afr[mf], bfr[nf], acc[mf][nf], 0, 0, 0);
    __syncthreads();
  }

  // ---- epilogue: +b1, store h (bf16), partial column stats ----
  const int n0 = wave * 128;
#pragma unroll
  for (int nf = 0; nf < 8; nf++) {
    const int col = n0 + nf * 16 + r16;
    const float bv = b1[col];
    float s1 = 0.f, s2 = 0.f;
#pragma unroll
    for (int mf = 0; mf < 4; mf++) {
#pragma unroll
      for (int p = 0; p < 4; p++) {
        float v = acc[mf][nf][p] + bv;
        int rl = mf * 16 + q * 4 + p;
        hbuf[(size_t)(row0 + rl) * DH + col] = f2bf(v);
        s1 += v; s2 += v * v;
      }
    }
    s1 += __shfl_xor(s1, 16); s1 += __shfl_xor(s1, 32);
    s2 += __shfl_xor(s2, 16); s2 += __shfl_xor(s2, 32);
    if (q == 0) { psum[col * MT1 + mtile] = s1; psumsq[col * MT1 + mtile] = s2; }
  }
}

// ---------------------------------------------------------------------------
// k2: reduce partials -> affine coeffs  a = gamma*rsqrt(var+eps), d = beta - mean*a
// grid: 512 blocks x 64 threads (one wave per column)
// ---------------------------------------------------------------------------
__global__ void k2_stats(const float* __restrict__ psum, const float* __restrict__ psumsq,
                         const float* __restrict__ gamma, const float* __restrict__ beta,
                         float* __restrict__ coef) {
  const int col = blockIdx.x, lane = threadIdx.x;
  float s1 = 0.f, s2 = 0.f;
  for (int i = lane; i < MT1; i += 64) { s1 += psum[col * MT1 + i]; s2 += psumsq[col * MT1 + i]; }
#pragma unroll
  for (int d = 1; d < 64; d <<= 1) { s1 += __shfl_xor(s1, d); s2 += __shfl_xor(s2, d); }
  if (lane == 0) {
    const float inv = 1.0f / (float)M;
    float mean = s1 * inv;
    float var  = s2 * inv - mean * mean;
    float a = gamma[col] * rsqrtf(var + 1e-5f);
    coef[col]      = a;
    coef[DH + col] = beta[col] - mean * a;
  }
}

// ---------------------------------------------------------------------------
// k3: out = relu(h*a + d) @ W2 + b2
// grid: 2048 blocks, 256 threads (4 waves); wave w: rows 0..63 x cols [w*64, w*64+64)
// ---------------------------------------------------------------------------
__global__ __launch_bounds__(256) void k3_gemm2(
    const unsigned short* __restrict__ hbuf, const unsigned short* __restrict__ W2T,
    const float* __restrict__ coef, const float* __restrict__ b2, float* __restrict__ out) {
  __shared__ __align__(16) unsigned short As[64][40];
  __shared__ __align__(16) unsigned short Bs[DO][40];
  __shared__ float aC[DH], dC[DH];

  const int tid   = threadIdx.x;
  const int mtile = blockIdx.x;
  const int row0  = mtile * 64;

  aC[tid] = coef[tid];            aC[tid + 256] = coef[tid + 256];
  dC[tid] = coef[DH + tid];       dC[tid + 256] = coef[DH + 256 + tid];
  __syncthreads();

  const int wave = tid >> 6, lane = tid & 63;
  const int q = lane >> 4, r16 = lane & 15;
  const int gr = tid >> 2, sub = tid & 3;

  f32x4 acc[4][4] = {};

  for (int k0 = 0; k0 < DH; k0 += 32) {
    // ---- stage A: load h bf16, apply affine + relu, back to bf16 ----
    {
      short8 hv = *(const short8*)(hbuf + (size_t)(row0 + gr) * DH + k0 + sub * 8);
      short8 pk;
#pragma unroll
      for (int j = 0; j < 8; j++) {
        int k = k0 + sub * 8 + j;
        float f = bf2f((unsigned short)hv[j]);
        f = f * aC[k] + dC[k];
        f = f > 0.f ? f : 0.f;
        pk[j] = (short)f2bf(f);
      }
      *(short8*)&As[gr][sub * 8] = pk;
    }
    // ---- stage B: copy W2T[n][k0..k0+31] for all 256 n ----
    {
      const unsigned short* src = W2T + tid * DH + k0;
#pragma unroll
      for (int i = 0; i < 4; i++)
        *(short8*)&Bs[tid][i * 8] = *(const short8*)(src + i * 8);
    }
    __syncthreads();

    const int n0 = wave * 64;
    bf16x8 afr[4], bfr[4];
#pragma unroll
    for (int mf = 0; mf < 4; mf++) afr[mf] = *(const bf16x8*)&As[mf * 16 + r16][q * 8];
#pragma unroll
    for (int nf = 0; nf < 4; nf++) bfr[nf] = *(const bf16x8*)&Bs[n0 + nf * 16 + r16][q * 8];
#pragma unroll
    for (int mf = 0; mf < 4; mf++)
#pragma unroll
      for (int nf = 0; nf < 4; nf++)
        acc[mf][nf] = __builtin_amdgcn_mfma_f32_16x16x32_bf16(afr[mf], bfr[nf], acc[mf][nf], 0, 0, 0);
    __syncthreads();
  }

  const int n0 = wave * 64;
#pragma unroll
  for (int nf = 0; nf < 4; nf++) {
    const int col = n0 + nf * 16 + r16;
    const float bv = b2[col];
#pragma unroll
    for (int mf = 0; mf < 4; mf++) {
#pragma unroll
      for (int p = 0; p < 4; p++) {
        int rl = mf * 16 + q * 4 + p;
        out[(size_t)(row0 + rl) * DO + col] = acc[mf][nf][p] + bv;
      }
    }
  }
}

// ---------------------------------------------------------------------------
// workspace layout (bytes):
//   [0,256K)        W1T bf16 [512][256]
//   [256K,512K)     W2T bf16 [256][512]
//   [512K,516K)     coef f32 [1024] (a then d)
//   [1M,5M)         psum   f32 [512][2048]
//   [5M,9M)         psumsq f32 [512][2048]
//   [16M,144M)      h bf16 [131072][512]
// total need ~151 MB
// ---------------------------------------------------------------------------
extern "C" void kernel_launch(void* const* d_in, const int* in_sizes, int n_in,
                              void* d_out, int out_size, void* d_ws, size_t ws_size,
                              hipStream_t stream) {
  const float* z     = (const float*)d_in[0];
  const int*   tbl   = (const int*)d_in[1];
  const float* W1    = (const float*)d_in[2];
  const float* b1    = (const float*)d_in[3];
  const float* gamma = (const float*)d_in[4];
  const float* beta  = (const float*)d_in[5];
  const float* W2    = (const float*)d_in[6];
  const float* b2    = (const float*)d_in[7];
  float* out = (float*)d_out;

  char* ws = (char*)d_ws;
  unsigned short* W1T  = (unsigned short*)(ws);
  unsigned short* W2T  = (unsigned short*)(ws + (256 << 10));
  float*          coef = (float*)(ws + (512 << 10));
  float*          psum = (float*)(ws + (1 << 20));
  float*          psq  = (float*)(ws + (5 << 20));
  unsigned short* hbuf = (unsigned short*)(ws + (16 << 20));

  prep_kernel<<<512, 256, 0, stream>>>(W1, W2, W1T, W2T);
  k1_gemm1<<<MT1, 256, 0, stream>>>(z, tbl, W1T, b1, hbuf, psum, psq);
  k2_stats<<<DH, 64, 0, stream>>>(psum, psq, gamma, beta, coef);
  k3_gemm2<<<MT1, 256, 0, stream>>>(hbuf, W2T, coef, b2, out);
}